// Round 6
// baseline (1357.967 us; speedup 1.0000x reference)
//
#include <hip/hip_runtime.h>
#include <math.h>

constexpr int F_IN = 20;
constexpr int DDIM = 256;

typedef __attribute__((ext_vector_type(8))) short bf16x8;
typedef __attribute__((ext_vector_type(4))) float f32x4;
typedef __attribute__((ext_vector_type(2))) float f32x2;
typedef __attribute__((ext_vector_type(4))) unsigned int u32x4;

__device__ __forceinline__ float b2f(unsigned short u){
  union { unsigned int i; float f; } x; x.i = ((unsigned int)u) << 16; return x.f;
}
__device__ __forceinline__ unsigned short f2b(float f){
  union { float f; unsigned int i; } x; x.f = f;
  unsigned int r = x.i + 0x7fffu + ((x.i >> 16) & 1u);
  return (unsigned short)(r >> 16);
}

// ---- packed f32 (VOP3P) helpers: 2 fp32 per instruction ----
__device__ __forceinline__ f32x2 pk_add(f32x2 a, f32x2 b){ f32x2 d; asm("v_pk_add_f32 %0, %1, %2" : "=v"(d) : "v"(a), "v"(b)); return d; }
__device__ __forceinline__ f32x2 pk_mul(f32x2 a, f32x2 b){ f32x2 d; asm("v_pk_mul_f32 %0, %1, %2" : "=v"(d) : "v"(a), "v"(b)); return d; }
__device__ __forceinline__ f32x2 pk_fma(f32x2 a, f32x2 b, f32x2 c){ f32x2 d; asm("v_pk_fma_f32 %0, %1, %2, %3" : "=v"(d) : "v"(a), "v"(b), "v"(c)); return d; }

// unpack u32 holding 2 bf16 -> 2 f32
__device__ __forceinline__ f32x2 unpk(unsigned int w){
  union { unsigned int u; float f; } lo, hi;
  lo.u = w << 16; hi.u = w & 0xFFFF0000u;
  f32x2 r; r.x = lo.f; r.y = hi.f; return r;
}

// 4-lane butterfly sum via DPP quad-perm (xor1 = 0xB1, xor2 = 0x4E), no LDS pipe
__device__ __forceinline__ float dpp_sum4(float p){
  int q1 = __builtin_amdgcn_mov_dpp(__float_as_int(p), 0xB1, 0xF, 0xF, true);
  p += __int_as_float(q1);
  int q2 = __builtin_amdgcn_mov_dpp(__float_as_int(p), 0x4E, 0xF, 0xF, true);
  return p + __int_as_float(q2);
}

__device__ __forceinline__ void gload_lds16(const unsigned short* g, unsigned short* l){
  __builtin_amdgcn_global_load_lds(
      (const __attribute__((address_space(1))) void*)g,
      (__attribute__((address_space(3))) void*)l, 16, 0, 0);
}

// ---------------- edge preprocessing ----------------
__global__ __launch_bounds__(256) void edge_prep_k(
    const int* __restrict__ ei, const float* __restrict__ pos,
    const float* __restrict__ mw1, const float* __restrict__ mb1,
    const float* __restrict__ mw2, const float* __restrict__ mb2,
    float* __restrict__ ew, int* __restrict__ cnt, int E)
{
  int t = blockIdx.x*256 + threadIdx.x;
  if (t >= E) return;
  int s = ei[t], d = ei[E + t];
  float dx = pos[s*3+0]-pos[d*3+0];
  float dy = pos[s*3+1]-pos[d*3+1];
  float dz = pos[s*3+2]-pos[d*3+2];
  float dist = sqrtf(dx*dx+dy*dy+dz*dz);
  float o = mb2[0];
  #pragma unroll
  for (int j=0;j<32;j++){
    float hj = fmaxf(dist*mw1[j]+mb1[j], 0.f);
    o += hj*mw2[j];
  }
  o = fmaxf(o, 0.f);
  ew[t] = o;
  atomicAdd(&cnt[d], 1);
}

// ---------------- scans (counting sort by dst) ----------------
__global__ __launch_bounds__(512) void scan1_k(const int* __restrict__ cnt, int* __restrict__ offs,
                                               int* __restrict__ bsum, int n)
{
  __shared__ int t[512];
  int tid = threadIdx.x;
  int i = blockIdx.x*512 + tid;
  int v = (i < n) ? cnt[i] : 0;
  t[tid] = v;
  __syncthreads();
  for (int s = 1; s < 512; s <<= 1) {
    int y = (tid >= s) ? t[tid - s] : 0;
    __syncthreads();
    if (tid >= s) t[tid] += y;
    __syncthreads();
  }
  if (i < n) offs[i] = t[tid] - v;
  if (tid == 511) bsum[blockIdx.x] = t[511];
}

__global__ __launch_bounds__(512) void scan2_k(const int* __restrict__ bsum, int* __restrict__ bpre, int nb)
{
  __shared__ int t[512];
  int tid = threadIdx.x;
  int v = (tid < nb) ? bsum[tid] : 0;
  t[tid] = v;
  __syncthreads();
  for (int s = 1; s < 512; s <<= 1) {
    int y = (tid >= s) ? t[tid - s] : 0;
    __syncthreads();
    if (tid >= s) t[tid] += y;
    __syncthreads();
  }
  bpre[tid] = t[tid] - v;
}

__global__ __launch_bounds__(512) void scan3_k(int* __restrict__ offs, const int* __restrict__ bpre, int n, int e)
{
  int i = blockIdx.x*512 + threadIdx.x;
  if (i < n) offs[i] += bpre[blockIdx.x];
  if (i == 0) offs[n] = e;
}

__global__ __launch_bounds__(256) void scatter_k(const int* __restrict__ ei, const float* __restrict__ ew,
    int* __restrict__ cur, int* __restrict__ ssrc, float* __restrict__ sew, int E)
{
  int t = blockIdx.x*256 + threadIdx.x;
  if (t >= E) return;
  int d = ei[E+t];
  int p = atomicAdd(&cur[d], 1);
  ssrc[p] = ei[t];
  sew[p] = ew[t];
}

// ---------------- graph segment offsets via binary search (batch sorted) ----------------
__global__ void gseg_k(const int* __restrict__ batch, int* __restrict__ goff, int n){
  int g = threadIdx.x;
  if (g > 64) return;
  int lo = 0, hi = n;
  while (lo < hi){ int mid = (lo + hi) >> 1; if (batch[mid] < g) lo = mid + 1; else hi = mid; }
  goff[g] = lo;
}

// ---------------- weight convert+transpose: Wt[layer][512 cols][256 k] bf16 ----------------
__global__ __launch_bounds__(256) void wt_k(const float* __restrict__ gwl, const float* __restrict__ gwr,
                                            unsigned short* __restrict__ Wt)
{
  __shared__ float t[64][65];
  int ct = blockIdx.x;
  int kt = blockIdx.y;
  int layer = blockIdx.z;
  int tid = threadIdx.x;
  int cbase = ct*64, k0 = kt*64;
  const float* src = (cbase < 256) ? (gwl + (size_t)layer*65536) : (gwr + (size_t)layer*65536);
  int csrc0 = (cbase < 256) ? cbase : cbase - 256;
  #pragma unroll
  for (int j = 0; j < 16; ++j){
    int idx = j*256 + tid;
    int kl = idx >> 6, cl = idx & 63;
    t[cl][kl] = src[(size_t)(k0 + kl)*256 + csrc0 + cl];
  }
  __syncthreads();
  #pragma unroll
  for (int j = 0; j < 16; ++j){
    int idx = j*256 + tid;
    int cl = idx >> 6, kl = idx & 63;
    Wt[(size_t)layer*131072 + (size_t)(cbase + cl)*256 + k0 + kl] = f2b(t[cl][kl]);
  }
}

// ---------------- h0 = x @ w_in + b_in (f32 + bf16 mirror) ----------------
__global__ __launch_bounds__(256) void h0_k(const float* __restrict__ x, const float* __restrict__ w,
    const float* __restrict__ b, float* __restrict__ h, unsigned short* __restrict__ hb, int n)
{
  __shared__ float xs[16][20];
  int row0 = blockIdx.x*16, tid = threadIdx.x;
  for (int idx = tid; idx < 16*20; idx += 256){
    int r = idx/20, c = idx%20;
    int rr = row0 + r;
    xs[r][c] = (rr < n) ? x[rr*20 + c] : 0.f;
  }
  __syncthreads();
  float bj = b[tid];
  float acc[16];
  #pragma unroll
  for (int r=0;r<16;r++) acc[r] = bj;
  for (int k=0;k<20;k++){
    float wv = w[k*256 + tid];
    #pragma unroll
    for (int r=0;r<16;r++) acc[r] += xs[r][k]*wv;
  }
  #pragma unroll
  for (int r=0;r<16;r++){
    int rr = row0 + r;
    if (rr < n){
      h[(size_t)rr*256 + tid] = acc[r];
      hb[(size_t)rr*256 + tid] = f2b(acc[r]);
    }
  }
}

// ---------------- bf16 MFMA GEMM via global_load_lds (pre-swizzled source) ----------------
__global__ __launch_bounds__(256) void gemm_mfma_k(
    const unsigned short* __restrict__ hb,   // [n][256] bf16
    const unsigned short* __restrict__ Wt,   // [512][256] bf16 (col-major weights)
    const float* __restrict__ bl, const float* __restrict__ br,
    unsigned short* __restrict__ out,        // [n][512] bf16
    int n)
{
  __shared__ short As[128*64];
  __shared__ short Bs[128*64];
  int tid = threadIdx.x;
  int lane = tid & 63, wid = tid >> 6;
  int wr = wid >> 1, wc = wid & 1;
  int row0 = blockIdx.x * 128;
  int col0 = blockIdx.y * 128;
  f32x4 acc[4][4] = {};

  // staging pattern: slice S (=wid*4+s) covers LDS rows 8S..8S+7 (linear dest);
  // lane i -> local row rl = i>>3, slot q = i&7; global col block = q ^ rl (inverse swizzle)
  int rl = lane >> 3;
  int csw = ((lane & 7) ^ rl) * 8;     // source column start (shorts), constant per lane

  for (int k0 = 0; k0 < 256; k0 += 64) {
    #pragma unroll
    for (int s = 0; s < 4; ++s) {
      int S = wid*4 + s;
      int ra = row0 + S*8 + rl; if (ra > n-1) ra = n-1;
      gload_lds16(hb + (size_t)ra*256 + k0 + csw, (unsigned short*)(As + S*512));
      int rb = col0 + S*8 + rl;
      gload_lds16(Wt + (size_t)rb*256 + k0 + csw, (unsigned short*)(Bs + S*512));
    }
    __syncthreads();
    #pragma unroll
    for (int kk = 0; kk < 2; ++kk) {
      bf16x8 a[4], b[4];
      #pragma unroll
      for (int mi = 0; mi < 4; ++mi) {
        int r = wr*64 + mi*16 + (lane & 15);
        int q = (kk*4 + (lane >> 4)) ^ (r & 7);
        a[mi] = *(const bf16x8*)(As + r*64 + q*8);
      }
      #pragma unroll
      for (int ni = 0; ni < 4; ++ni) {
        int r = wc*64 + ni*16 + (lane & 15);
        int q = (kk*4 + (lane >> 4)) ^ (r & 7);
        b[ni] = *(const bf16x8*)(Bs + r*64 + q*8);
      }
      #pragma unroll
      for (int mi = 0; mi < 4; ++mi)
        #pragma unroll
        for (int ni = 0; ni < 4; ++ni)
          acc[mi][ni] = __builtin_amdgcn_mfma_f32_16x16x32_bf16(a[mi], b[ni], acc[mi][ni], 0, 0, 0);
    }
    __syncthreads();
  }

  const float* bias = (col0 < 256) ? bl : br;
  int cb = (col0 < 256) ? col0 : col0 - 256;
  #pragma unroll
  for (int ni = 0; ni < 4; ++ni) {
    int coff = wc*64 + ni*16 + (lane & 15);
    int col = col0 + coff;
    float bv = bias[cb + coff];
    #pragma unroll
    for (int mi = 0; mi < 4; ++mi) {
      #pragma unroll
      for (int e = 0; e < 4; ++e) {
        int row = row0 + wr*64 + mi*16 + (lane >> 4)*4 + e;
        if (row < n) out[(size_t)row*512 + col] = f2b(acc[mi][ni][e] + bv);
      }
    }
  }
}

// ---------------- fused GATv2: 4 edges/iter, 16 lanes/edge, per-head softmax, pk-f32 math ----
__global__ __launch_bounds__(256) void gat_agg_k(
    const unsigned short* __restrict__ xlr,  // [n][512] bf16: cols 0-255 xl, 256-511 xr
    const int* __restrict__ offs, const int* __restrict__ ssrc, const float* __restrict__ sew,
    const float* __restrict__ we, const float* __restrict__ att, const float* __restrict__ bias,
    float* __restrict__ h, unsigned short* __restrict__ hb, float* __restrict__ hout,
    const float* __restrict__ gw, const float* __restrict__ gb, float* __restrict__ logit, int n)
{
  int wid = blockIdx.x*4 + (threadIdx.x >> 6);
  if (wid >= n) return;
  int lane = threadIdx.x & 63;
  int g = lane >> 4, l = lane & 15;
  int c0 = l*16;                       // this lane's 16 channels (single head l>>2)

  // per-lane params as f32x2 pairs
  f32x2 xr2[8], we2[8], at2[8];
  {
    const u32x4* xrp = (const u32x4*)(xlr + (size_t)wid*512 + 256 + c0);
    u32x4 r0 = xrp[0], r1 = xrp[1];
    #pragma unroll
    for (int j=0;j<4;j++){ xr2[j] = unpk(r0[j]); xr2[4+j] = unpk(r1[j]); }
    #pragma unroll
    for (int q=0;q<4;q++){
      float4 wv = *(const float4*)(we + c0 + q*4);
      float4 av = *(const float4*)(att + c0 + q*4);
      we2[q*2+0].x=wv.x; we2[q*2+0].y=wv.y; we2[q*2+1].x=wv.z; we2[q*2+1].y=wv.w;
      at2[q*2+0].x=av.x; at2[q*2+0].y=av.y; at2[q*2+1].x=av.z; at2[q*2+1].y=av.w;
    }
  }
  const f32x2 k02 = {0.2f, 0.2f};

  float m = -1e30f, s = 0.f;
  f32x2 a2[8];
  #pragma unroll
  for (int j=0;j<8;j++){ a2[j].x = 0.f; a2[j].y = 0.f; }

  int k = offs[wid] + g, kend = offs[wid+1];
  float ewv = 0.f;
  u32x4 xa = {0,0,0,0};
  u32x4 xbv = {0,0,0,0};
  if (k < kend){
    unsigned off = (unsigned)ssrc[k] << 9;   // row*512 shorts
    ewv = sew[k];
    const u32x4* xp = (const u32x4*)(xlr + off + c0);
    xa = xp[0]; xbv = xp[1];
  }
  while (__any(k < kend)) {
    bool act = (k < kend);
    u32x4 ca = xa, cb = xbv; float ce = ewv;
    k += 4;
    if (k < kend){
      unsigned off = (unsigned)ssrc[k] << 9;
      ewv = sew[k];
      const u32x4* xp = (const u32x4*)(xlr + off + c0);
      xa = xp[0]; xbv = xp[1];
    }
    f32x2 xj2[8];
    #pragma unroll
    for (int j=0;j<4;j++){ xj2[j] = unpk(ca[j]); xj2[4+j] = unpk(cb[j]); }
    f32x2 ce2; ce2.x = ce; ce2.y = ce;
    f32x2 p2; p2.x = 0.f; p2.y = 0.f;
    #pragma unroll
    for (int j=0;j<8;j++){
      f32x2 t = pk_fma(ce2, we2[j], pk_add(xj2[j], xr2[j]));
      f32x2 u = pk_mul(t, k02);
      t.x = fmaxf(t.x, u.x); t.y = fmaxf(t.y, u.y);   // leaky-relu
      p2 = pk_fma(t, at2[j], p2);
    }
    float p = p2.x + p2.y;
    p = dpp_sum4(p);                   // per-head logit (4 lanes share a head)
    if (!act) p = -1e30f;
    if (__any(p > m + 8.f)) {
      float mn = fmaxf(m, p);
      float corr = __expf(m - mn);
      float wv = act ? __expf(p - mn) : 0.f;
      s = s*corr + wv;
      f32x2 c2; c2.x = corr; c2.y = corr;
      f32x2 w2; w2.x = wv;   w2.y = wv;
      #pragma unroll
      for (int j=0;j<8;j++) a2[j] = pk_fma(a2[j], c2, pk_mul(w2, xj2[j]));
      m = mn;
    } else {
      float wv = act ? __expf(p - m) : 0.f;
      s += wv;
      f32x2 w2; w2.x = wv; w2.y = wv;
      #pragma unroll
      for (int j=0;j<8;j++) a2[j] = pk_fma(w2, xj2[j], a2[j]);
    }
  }

  // flash-merge the 4 edge-groups per head (butterfly over lane bits 4,5)
  #pragma unroll
  for (int d = 16; d <= 32; d <<= 1) {
    float mo = __shfl_xor(m, d);
    float so = __shfl_xor(s, d);
    float mn = fmaxf(m, mo);
    float cs = __expf(m - mn), co = __expf(mo - mn);
    s = s*cs + so*co;
    f32x2 cs2; cs2.x = cs; cs2.y = cs;
    f32x2 co2; co2.x = co; co2.y = co;
    #pragma unroll
    for (int j=0;j<8;j++){
      f32x2 ao;
      ao.x = __shfl_xor(a2[j].x, d);
      ao.y = __shfl_xor(a2[j].y, d);
      a2[j] = pk_add(pk_mul(a2[j], cs2), pk_mul(ao, co2));
    }
    m = mn;
  }

  // epilogue: all 64 lanes write 4 contiguous channels (wave = contiguous 1KB)
  float inv = 1.f/(s + 1e-16f);
  f32x2 alo, ahi;
  if (g == 0)      { alo = a2[0]; ahi = a2[1]; }
  else if (g == 1) { alo = a2[2]; ahi = a2[3]; }
  else if (g == 2) { alo = a2[4]; ahi = a2[5]; }
  else             { alo = a2[6]; ahi = a2[7]; }
  int cw = l*16 + g*4;
  size_t base = (size_t)wid*256 + cw;
  float4 hv = *(const float4*)(h + base);
  float4 b4 = *(const float4*)(bias + cw);
  float4 o;
  o.x = fmaxf(hv.x + alo.x*inv + b4.x, 0.f);
  o.y = fmaxf(hv.y + alo.y*inv + b4.y, 0.f);
  o.z = fmaxf(hv.z + ahi.x*inv + b4.z, 0.f);
  o.w = fmaxf(hv.w + ahi.y*inv + b4.w, 0.f);
  *(float4*)(h + base) = o;
  ushort4 ob;
  ob.x = f2b(o.x); ob.y = f2b(o.y); ob.z = f2b(o.z); ob.w = f2b(o.w);
  *(ushort4*)(hb + base) = ob;
  if (hout) *(float4*)(hout + base) = o;

  // fused pooling gate logit (pooling layers only)
  if (gw) {
    float4 gv = *(const float4*)(gw + cw);
    float p = o.x*gv.x + o.y*gv.y + o.z*gv.z + o.w*gv.w;
    p += __shfl_xor(p, 1);
    p += __shfl_xor(p, 2);
    p += __shfl_xor(p, 4);
    p += __shfl_xor(p, 8);
    p += __shfl_xor(p, 16);
    p += __shfl_xor(p, 32);
    if (lane == 0) logit[wid] = p + gb[0];
  }
}

// ---------------- pooling (reads bf16 mirror) ----------------
__global__ __launch_bounds__(1024) void pool_k(const unsigned short* __restrict__ hb,
    const float* __restrict__ logit, const int* __restrict__ goff, float* __restrict__ hbar)
{
  __shared__ float red[1024];
  __shared__ float mS, sS;
  int g = blockIdx.x, tid = threadIdx.x;
  int b0 = goff[g], b1 = goff[g+1];
  float lm = -INFINITY;
  for (int i = b0 + tid; i < b1; i += 1024) lm = fmaxf(lm, logit[i]);
  red[tid] = lm;
  __syncthreads();
  for (int s = 512; s > 0; s >>= 1){
    if (tid < s) red[tid] = fmaxf(red[tid], red[tid+s]);
    __syncthreads();
  }
  if (tid == 0) mS = red[0];
  __syncthreads();
  float m = mS;
  float sw = 0.f;
  for (int i = b0 + tid; i < b1; i += 1024) sw += __expf(logit[i] - m);
  __syncthreads();
  red[tid] = sw;
  __syncthreads();
  for (int s = 512; s > 0; s >>= 1){
    if (tid < s) red[tid] += red[tid+s];
    __syncthreads();
  }
  if (tid == 0) sS = red[0];
  __syncthreads();
  float sden = sS;
  int ch = tid & 255, rs = tid >> 8;
  float acc = 0.f;
  for (int i = b0 + rs; i < b1; i += 4)
    acc += __expf(logit[i] - m) * b2f(hb[(size_t)i*256 + ch]);
  __syncthreads();
  red[tid] = acc;
  __syncthreads();
  if (rs == 0){
    float a = red[ch] + red[256+ch] + red[512+ch] + red[768+ch];
    hbar[g*256 + ch] = a/(sden + 1e-16f);
  }
}

// ---------------- small row GEMM ----------------
template<int K, bool RELU>
__global__ __launch_bounds__(256) void rowgemm_k(const float* __restrict__ A, const float* __restrict__ W,
    const float* __restrict__ bias, float* __restrict__ out, int ostride)
{
  __shared__ float ar[K];
  int row = blockIdx.x;
  int tid = threadIdx.x;
  for (int i = tid; i < K; i += 256) ar[i] = A[(size_t)row*K + i];
  __syncthreads();
  float acc = bias[tid];
  for (int k = 0; k < K; ++k) acc += ar[k]*W[k*256 + tid];
  if (RELU) acc = fmaxf(acc, 0.f);
  out[(size_t)row*ostride + tid] = acc;
}

extern "C" void kernel_launch(void* const* d_in, const int* in_sizes, int n_in,
                              void* d_out, int out_size, void* d_ws, size_t ws_size,
                              hipStream_t stream)
{
  const float* x     = (const float*)d_in[0];
  const float* pos   = (const float*)d_in[1];
  const int*   ei    = (const int*)d_in[2];
  const int*   batch = (const int*)d_in[3];
  const float* mw1   = (const float*)d_in[4];
  const float* mb1   = (const float*)d_in[5];
  const float* mw2   = (const float*)d_in[6];
  const float* mb2   = (const float*)d_in[7];
  const float* w_in  = (const float*)d_in[8];
  const float* b_in  = (const float*)d_in[9];
  const float* gwl   = (const float*)d_in[10];
  const float* gbl   = (const float*)d_in[11];
  const float* gwr   = (const float*)d_in[12];
  const float* gbr   = (const float*)d_in[13];
  const float* gwe   = (const float*)d_in[14];
  const float* gatt  = (const float*)d_in[15];
  const float* gbias = (const float*)d_in[16];
  const float* gate_w= (const float*)d_in[17];
  const float* gate_b= (const float*)d_in[18];
  const float* nn_w  = (const float*)d_in[19];
  const float* nn_b  = (const float*)d_in[20];
  const float* ow1   = (const float*)d_in[21];
  const float* ob1   = (const float*)d_in[22];
  const float* ow2   = (const float*)d_in[23];
  const float* ob2   = (const float*)d_in[24];

  const int N = in_sizes[0] / F_IN;
  const int E = in_sizes[2] / 2;

  char* ws = (char*)d_ws;
  size_t woff = 0;
  auto alloc = [&](size_t bytes) -> void* {
    void* p = ws + woff;
    woff = (woff + bytes + 255) & ~(size_t)255;
    return p;
  };
  float* ew    = (float*)alloc((size_t)E*4);
  int*   cnt   = (int*)  alloc((size_t)N*4);
  int*   offs  = (int*)  alloc((size_t)(N+1)*4);
  int*   cur   = (int*)  alloc((size_t)N*4);
  int*   bsum  = (int*)  alloc(512*4);
  int*   bpre  = (int*)  alloc(512*4);
  int*   ssrc  = (int*)  alloc((size_t)E*4);
  float* sew   = (float*)alloc((size_t)E*4);
  float* h     = (float*)alloc((size_t)N*DDIM*4);
  unsigned short* hb  = (unsigned short*)alloc((size_t)N*DDIM*2);
  unsigned short* xlr = (unsigned short*)alloc((size_t)N*512*2);
  unsigned short* Wt  = (unsigned short*)alloc((size_t)6*512*256*2);
  float* logit = (float*)alloc((size_t)N*4);
  int*   goff  = (int*)  alloc(68*4);
  float* hbar  = (float*)alloc(64*DDIM*4);
  float* zcat  = (float*)alloc(64*768*4);
  float* t1    = (float*)alloc(64*DDIM*4);
  (void)ws_size; (void)n_in; (void)out_size;

  hipMemsetAsync(cnt, 0, (size_t)N*4, stream);

  int eb = (E + 255)/256;
  edge_prep_k<<<eb, 256, 0, stream>>>(ei, pos, mw1, mb1, mw2, mb2, ew, cnt, E);
  int nb = (N + 511)/512;
  scan1_k<<<nb, 512, 0, stream>>>(cnt, offs, bsum, N);
  scan2_k<<<1, 512, 0, stream>>>(bsum, bpre, nb);
  scan3_k<<<nb, 512, 0, stream>>>(offs, bpre, N, E);
  hipMemcpyAsync(cur, offs, (size_t)N*4, hipMemcpyDeviceToDevice, stream);
  scatter_k<<<eb, 256, 0, stream>>>(ei, ew, cur, ssrc, sew, E);

  gseg_k<<<1, 128, 0, stream>>>(batch, goff, N);
  wt_k<<<dim3(8,4,6), 256, 0, stream>>>(gwl, gwr, Wt);

  h0_k<<<(N + 15)/16, 256, 0, stream>>>(x, w_in, b_in, h, hb, N);

  int gx = (N + 127)/128;
  int wavegrid = (N + 3)/4;
  for (int i = 0; i < 6; ++i) {
    gemm_mfma_k<<<dim3(gx, 4), 256, 0, stream>>>(hb, Wt + (size_t)i*131072,
        gbl + i*256, gbr + i*256, xlr, N);
    float* hout = (i == 5) ? (float*)d_out : (float*)nullptr;
    int blk = i >> 1;
    const float* gwp = (i & 1) ? (gate_w + blk*256) : (const float*)nullptr;
    const float* gbp = (i & 1) ? (gate_b + blk) : (const float*)nullptr;
    gat_agg_k<<<wavegrid, 256, 0, stream>>>(xlr, offs, ssrc, sew,
        gwe + i*256, gatt + i*256, gbias + i*256, h, hb, hout, gwp, gbp, logit, N);
    if (i & 1) {
      pool_k<<<64, 1024, 0, stream>>>(hb, logit, goff, hbar);
      rowgemm_k<256,false><<<64, 256, 0, stream>>>(hbar, nn_w + (size_t)blk*65536,
          nn_b + blk*256, zcat + blk*256, 768);
    }
  }
  rowgemm_k<768,true><<<64, 256, 0, stream>>>(zcat, ow1, ob1, t1, 256);
  rowgemm_k<256,false><<<64, 256, 0, stream>>>(t1, ow2, ob2, (float*)d_out + (size_t)N*DDIM, 256);
}